// Round 6
// baseline (145.699 us; speedup 1.0000x reference)
//
#include <hip/hip_runtime.h>

#define NORG 13
#define NCH  14
#define VOX  (48 * 256 * 256)   // voxels per (batch, channel) plane
#define EPSF 1e-5f
#define CHUNK 8192              // voxels per block (best measured)
#define NCHUNK (VOX / CHUNK)    // 384 chunks per batch
#define ITER (CHUNK / 4 / 256)  // 8 float4-iterations per pass
#define COMBO_STRIDE 16         // padded ws slots per (replica, combo)
#define NREP 8                  // global accumulator replicas
#define MAXCOMBO 26             // B(=2) * NORG
// ws layout (floats): [0..15] counter+pad, [16 ...] NREP banks of 26*16

typedef float f4 __attribute__((ext_vector_type(4)));
typedef int   i4 __attribute__((ext_vector_type(4)));

__global__ __launch_bounds__(256) void dice_fused(
    const float* __restrict__ pred1, const float* __restrict__ pred2,
    const int* __restrict__ tgt, float* __restrict__ ws,
    float* __restrict__ out, int B, int nblocks)
{
    const int b     = blockIdx.y;
    const int chunk = blockIdx.x;
    const size_t v0 = (size_t)chunk * CHUNK;
    float* banks = ws + 16;

    __shared__ unsigned char t_lds[CHUNK];    // target chunk, staged ONCE
    __shared__ float red[4][16][NORG * 5];    // per (wave, 4-lane-group) partials
    __shared__ float red2[MAXCOMBO * 5];
    __shared__ int   last_flag;

    // ---- stage target chunk into LDS as uchar (nontemporal: read-once) ----
    const i4* tb = (const i4*)(tgt + (size_t)b * VOX + v0);
    uchar4* tl4 = (uchar4*)t_lds;
#pragma unroll
    for (int i = 0; i < ITER; ++i) {
        const i4 t = __builtin_nontemporal_load(tb + i * 256 + threadIdx.x);
        tl4[i * 256 + threadIdx.x] =
            make_uchar4((unsigned char)t.x, (unsigned char)t.y,
                        (unsigned char)t.z, (unsigned char)t.w);
    }
    __syncthreads();

    const uchar4* tl = (const uchar4*)t_lds;
    const int lane = threadIdx.x & 63;
    const int wid  = threadIdx.x >> 6;

    // ---- 13 channel passes, both stages fused (2 HBM streams per pass) ----
    for (int o = 0; o < NORG; ++o) {
        const int ch = o + 1;
        const f4* p1 = (const f4*)(pred1 + ((size_t)b * NCH + ch) * VOX + v0);
        const f4* p2 = (const f4*)(pred2 + ((size_t)b * NCH + ch) * VOX + v0);

        float i1 = 0.f, s1 = 0.f, i2 = 0.f, s2 = 0.f, cn = 0.f;
#pragma unroll
        for (int i = 0; i < ITER; ++i) {
            const int idx = i * 256 + threadIdx.x;
            const uchar4 t = tl[idx];
            const f4 a = __builtin_nontemporal_load(p1 + idx);
            const f4 c = __builtin_nontemporal_load(p2 + idx);
            const float m0 = (t.x == ch) ? 1.f : 0.f;
            const float m1 = (t.y == ch) ? 1.f : 0.f;
            const float m2 = (t.z == ch) ? 1.f : 0.f;
            const float m3 = (t.w == ch) ? 1.f : 0.f;
            s1 += a.x * a.x + a.y * a.y + a.z * a.z + a.w * a.w;
            s2 += c.x * c.x + c.y * c.y + c.z * c.z + c.w * c.w;
            i1 += m0 * a.x + m1 * a.y + m2 * a.z + m3 * a.w;
            i2 += m0 * c.x + m1 * c.y + m2 * c.z + m3 * c.w;
            cn += (m0 + m1) + (m2 + m3);
        }

        // cheap tail: 2-level shuffle (4-lane groups) + plain ds_write
        float vals[5] = {i1, s1, i2, s2, cn};
#pragma unroll
        for (int s = 0; s < 5; ++s) {
            float r = vals[s];
            r += __shfl_xor(r, 1, 64);
            r += __shfl_xor(r, 2, 64);
            if ((lane & 3) == 0) red[wid][lane >> 2][o * 5 + s] = r;
        }
    }

    __syncthreads();
    // block-end combine: 65 slots x 64 partials -> one global atomic per slot
    if (threadIdx.x < NORG * 5) {
        float s = 0.f;
#pragma unroll
        for (int w = 0; w < 4; ++w)
#pragma unroll
            for (int g = 0; g < 16; ++g)
                s += red[w][g][threadIdx.x];
        const int o  = threadIdx.x / 5;
        const int sl = threadIdx.x % 5;
        const int bo = b * NORG + o;
        const int rep = blockIdx.x & (NREP - 1);
        atomicAdd(&banks[(rep * MAXCOMBO + bo) * COMBO_STRIDE + sl], s);
    }

    // ---- completion detection: last block computes the final scalar ----
    __syncthreads();               // drains the atomicAdds (vmcnt) block-wide
    if (threadIdx.x == 0) {
        __threadfence();           // order partial adds before counter bump
        const unsigned old = atomicAdd((unsigned*)ws, 1u);
        last_flag = (old == (unsigned)(nblocks - 1));
    }
    __syncthreads();
    if (!last_flag) return;

    __threadfence();               // acquire side
    const int ncombo = B * NORG;
    if (threadIdx.x < ncombo * 5) {
        float s = 0.f;
#pragma unroll
        for (int r = 0; r < NREP; ++r)   // atomic-read: XCD-coherence-safe
            s += atomicAdd(&banks[(r * MAXCOMBO + threadIdx.x / 5) * COMBO_STRIDE
                                  + threadIdx.x % 5], 0.f);
        red2[threadIdx.x] = s;
    }
    __syncthreads();
    if (threadIdx.x == 0) {
        float total = 0.f;
        for (int b2 = 0; b2 < B; ++b2) {
            float d1 = 0.f, d2 = 0.f;
            for (int o = 0; o < NORG; ++o) {
                const float* a = red2 + (b2 * NORG + o) * 5;
                d1 += 2.f * a[0] / (a[1] + a[4] + EPSF);
                d2 += 2.f * a[2] / (a[3] + a[4] + EPSF);
            }
            total += 2.f - (d1 + d2) / (float)NORG;
        }
        out[0] = total / (float)B;
    }
}

extern "C" void kernel_launch(void* const* d_in, const int* in_sizes, int n_in,
                              void* d_out, int out_size, void* d_ws, size_t ws_size,
                              hipStream_t stream)
{
    const float* p1  = (const float*)d_in[0];
    const float* p2  = (const float*)d_in[1];
    const int*   tgt = (const int*)d_in[2];
    float*       out = (float*)d_out;
    float*       ws  = (float*)d_ws;

    const int B = in_sizes[2] / VOX;   // = 2 for the reference shapes
    const int nblocks = NCHUNK * B;

    // zero counter + replica banks (ws is poisoned once, never re-zeroed)
    hipMemsetAsync(d_ws, 0,
                   (size_t)(16 + NREP * MAXCOMBO * COMBO_STRIDE) * sizeof(float),
                   stream);

    dim3 grid(NCHUNK, B);              // 384 x 2 = 768 blocks, 3/CU exact
    dice_fused<<<grid, 256, 0, stream>>>(p1, p2, tgt, ws, out, B, nblocks);
}

// Round 7
// 115.884 us; speedup vs baseline: 1.2573x; 1.2573x over previous
//
#include <hip/hip_runtime.h>

#define NORG 13
#define NCH  14
#define VOX  (48 * 256 * 256)   // voxels per (batch, channel) plane
#define EPSF 1e-5f
#define CHUNK 8192              // voxels per block (best measured: rounds 2/4)
#define NCHUNK (VOX / CHUNK)    // 384 chunks per batch -> 768 blocks
#define ITER (CHUNK / 4 / 256)  // 8 float4-iterations per pass
#define COMBO_STRIDE 16         // padded ws slots per (replica, combo)
#define NREP 8                  // global accumulator replicas
#define MAXCOMBO 26             // B(=2) * NORG

typedef float f4 __attribute__((ext_vector_type(4)));
typedef int   i4 __attribute__((ext_vector_type(4)));

__global__ __launch_bounds__(256) void dice_partial(
    const float* __restrict__ pred1, const float* __restrict__ pred2,
    const int* __restrict__ tgt, float* __restrict__ acc_out)
{
    const int b     = blockIdx.y;
    const int chunk = blockIdx.x;
    const size_t v0 = (size_t)chunk * CHUNK;

    __shared__ unsigned char t_lds[CHUNK];    // target chunk, staged ONCE
    __shared__ float red[4][16][NORG * 5];    // per (wave, 4-lane-group) partials

    // ---- stage target chunk into LDS as uchar (nontemporal: read-once) ----
    const i4* tb = (const i4*)(tgt + (size_t)b * VOX + v0);
    uchar4* tl4 = (uchar4*)t_lds;
#pragma unroll
    for (int i = 0; i < ITER; ++i) {
        const i4 t = __builtin_nontemporal_load(tb + i * 256 + threadIdx.x);
        tl4[i * 256 + threadIdx.x] =
            make_uchar4((unsigned char)t.x, (unsigned char)t.y,
                        (unsigned char)t.z, (unsigned char)t.w);
    }
    __syncthreads();

    const uchar4* tl = (const uchar4*)t_lds;
    const int lane = threadIdx.x & 63;
    const int wid  = threadIdx.x >> 6;

    // ---- 13 channel passes, both stages fused (2 HBM streams per pass) ----
    for (int o = 0; o < NORG; ++o) {
        const int ch = o + 1;
        const f4* p1 = (const f4*)(pred1 + ((size_t)b * NCH + ch) * VOX + v0);
        const f4* p2 = (const f4*)(pred2 + ((size_t)b * NCH + ch) * VOX + v0);

        float i1 = 0.f, s1 = 0.f, i2 = 0.f, s2 = 0.f, cn = 0.f;
#pragma unroll
        for (int i = 0; i < ITER; ++i) {
            const int idx = i * 256 + threadIdx.x;
            const uchar4 t = tl[idx];
            const f4 a = __builtin_nontemporal_load(p1 + idx);
            const f4 c = __builtin_nontemporal_load(p2 + idx);
            const float m0 = (t.x == ch) ? 1.f : 0.f;
            const float m1 = (t.y == ch) ? 1.f : 0.f;
            const float m2 = (t.z == ch) ? 1.f : 0.f;
            const float m3 = (t.w == ch) ? 1.f : 0.f;
            s1 += a.x * a.x + a.y * a.y + a.z * a.z + a.w * a.w;
            s2 += c.x * c.x + c.y * c.y + c.z * c.z + c.w * c.w;
            i1 += m0 * a.x + m1 * a.y + m2 * a.z + m3 * a.w;
            i2 += m0 * c.x + m1 * c.y + m2 * c.z + m3 * c.w;
            cn += (m0 + m1) + (m2 + m3);
        }

        // cheap tail: 2-level shuffle (4-lane groups) + plain ds_write
        float vals[5] = {i1, s1, i2, s2, cn};
#pragma unroll
        for (int s = 0; s < 5; ++s) {
            float r = vals[s];
            r += __shfl_xor(r, 1, 64);
            r += __shfl_xor(r, 2, 64);
            if ((lane & 3) == 0) red[wid][lane >> 2][o * 5 + s] = r;
        }
    }

    __syncthreads();
    // block-end combine: 65 slots x 64 partials -> one global atomic per slot
    if (threadIdx.x < NORG * 5) {
        float s = 0.f;
#pragma unroll
        for (int w = 0; w < 4; ++w)
#pragma unroll
            for (int g = 0; g < 16; ++g)
                s += red[w][g][threadIdx.x];
        const int o  = threadIdx.x / 5;
        const int sl = threadIdx.x % 5;
        const int bo = b * NORG + o;
        const int rep = blockIdx.x & (NREP - 1);
        atomicAdd(&acc_out[(rep * MAXCOMBO + bo) * COMBO_STRIDE + sl], s);
    }
}

__global__ __launch_bounds__(256) void dice_final(
    const float* __restrict__ acc, float* __restrict__ out, int B)
{
    __shared__ float red2[MAXCOMBO * 5];
    const int ncombo = B * NORG;
    // parallel combine of the replica banks (130 threads, coalesced-ish)
    if (threadIdx.x < ncombo * 5) {
        const int co = threadIdx.x / 5;
        const int sl = threadIdx.x % 5;
        float s = 0.f;
#pragma unroll
        for (int r = 0; r < NREP; ++r)
            s += acc[(r * MAXCOMBO + co) * COMBO_STRIDE + sl];
        red2[threadIdx.x] = s;
    }
    __syncthreads();
    if (threadIdx.x == 0) {
        float total = 0.f;
        for (int b = 0; b < B; ++b) {
            float d1 = 0.f, d2 = 0.f;
            for (int o = 0; o < NORG; ++o) {
                const float* a = red2 + (b * NORG + o) * 5;
                d1 += 2.f * a[0] / (a[1] + a[4] + EPSF);
                d2 += 2.f * a[2] / (a[3] + a[4] + EPSF);
            }
            total += 2.f - (d1 + d2) / (float)NORG;
        }
        out[0] = total / (float)B;
    }
}

extern "C" void kernel_launch(void* const* d_in, const int* in_sizes, int n_in,
                              void* d_out, int out_size, void* d_ws, size_t ws_size,
                              hipStream_t stream)
{
    const float* p1  = (const float*)d_in[0];
    const float* p2  = (const float*)d_in[1];
    const int*   tgt = (const int*)d_in[2];
    float*       out = (float*)d_out;
    float*       acc = (float*)d_ws;

    const int B = in_sizes[2] / VOX;   // = 2 for the reference shapes

    // zero replica banks (ws is poisoned once, never re-zeroed)
    hipMemsetAsync(d_ws, 0,
                   (size_t)NREP * MAXCOMBO * COMBO_STRIDE * sizeof(float),
                   stream);

    dim3 grid(NCHUNK, B);              // 384 x 2 = 768 blocks, 3/CU exact
    dice_partial<<<grid, 256, 0, stream>>>(p1, p2, tgt, acc);
    dice_final<<<1, 256, 0, stream>>>(acc, out, B);
}